// Round 4
// baseline (669.075 us; speedup 1.0000x reference)
//
#include <hip/hip_runtime.h>

#define N_NODES 30000
#define N_EDGES 150000
#define N_REL 10
#define DIM 256

#define SORT_BLOCKS 120
#define SORT_CHUNK ((N_EDGES + SORT_BLOCKS - 1) / SORT_BLOCKS)  // 1250

#define SCAN_CHUNK 256
#define SCAN_BLOCKS ((N_NODES + SCAN_CHUNK - 1) / SCAN_CHUNK)   // 118

typedef __attribute__((ext_vector_type(8))) short bf16x8;
typedef __attribute__((ext_vector_type(4))) float f32x4;

__device__ __forceinline__ unsigned short f2bf(float f) {
  union { float f; unsigned int u; } v; v.f = f;
  unsigned int u = v.u;
  unsigned int r = u + 0x7fffu + ((u >> 16) & 1u);  // RNE
  return (unsigned short)(r >> 16);
}

// ---- preprocessing -------------------------------------------------------

__global__ void conv_x_kernel(const float* __restrict__ x,
                              unsigned short* __restrict__ xbf) {
  int idx = blockIdx.x * blockDim.x + threadIdx.x;  // one float4 each, exact grid
  float4 v = reinterpret_cast<const float4*>(x)[idx];
  ushort4 o;
  o.x = f2bf(v.x); o.y = f2bf(v.y); o.z = f2bf(v.z); o.w = f2bf(v.w);
  reinterpret_cast<ushort4*>(xbf)[idx] = o;
}

// wt[b][o][i] = W_b[i][o] (bf16), buckets: 0..9 fwd, 10..19 rev, 20 self
__global__ void conv_w_kernel(const float* __restrict__ Wf,
                              const float* __restrict__ Wr,
                              const float* __restrict__ Ws,
                              unsigned short* __restrict__ wt) {
  int idx = blockIdx.x * blockDim.x + threadIdx.x;  // exact grid 21*65536
  int b = idx >> 16;
  int t = idx & 65535;
  int o = t >> 8, i = t & 255;
  const float* src = (b < N_REL) ? (Wf + (size_t)b * 65536)
                   : (b < 2 * N_REL) ? (Wr + (size_t)(b - N_REL) * 65536)
                   : Ws;
  wt[idx] = f2bf(src[i * 256 + o]);
}

// ---- counting sort by relation (block-local hist, no global atomics) -----

__global__ void blockhist_kernel(const int* __restrict__ rel,
                                 int* __restrict__ block_counts) {
  __shared__ int h[N_REL];
  if (threadIdx.x < N_REL) h[threadIdx.x] = 0;
  __syncthreads();
  int beg = blockIdx.x * SORT_CHUNK;
  int end = min(beg + SORT_CHUNK, N_EDGES);
  for (int e = beg + threadIdx.x; e < end; e += blockDim.x)
    atomicAdd(&h[rel[e]], 1);
  __syncthreads();
  if (threadIdx.x < N_REL)
    block_counts[blockIdx.x * N_REL + threadIdx.x] = h[threadIdx.x];
}

__global__ void scan_rel_kernel(const int* __restrict__ block_counts,
                                int* __restrict__ rel_start,
                                int* __restrict__ block_offset) {
  __shared__ int tot[N_REL];
  int r = threadIdx.x;
  if (r < N_REL) {
    int s = 0;
    for (int b = 0; b < SORT_BLOCKS; ++b) s += block_counts[b * N_REL + r];
    tot[r] = s;
  }
  __syncthreads();
  if (threadIdx.x == 0) {
    int s = 0;
    for (int i = 0; i < N_REL; ++i) { rel_start[i] = s; s += tot[i]; }
    rel_start[N_REL] = s;
  }
  __syncthreads();
  if (r < N_REL) {
    int run = rel_start[r];
    for (int b = 0; b < SORT_BLOCKS; ++b) {
      block_offset[b * N_REL + r] = run;
      run += block_counts[b * N_REL + r];
    }
  }
}

__global__ void scatter2_kernel(const int* __restrict__ rel,
                                const int* __restrict__ block_offset,
                                int* __restrict__ perm) {
  __shared__ int cur[N_REL];
  if (threadIdx.x < N_REL)
    cur[threadIdx.x] = block_offset[blockIdx.x * N_REL + threadIdx.x];
  __syncthreads();
  int beg = blockIdx.x * SORT_CHUNK;
  int end = min(beg + SORT_CHUNK, N_EDGES);
  for (int e = beg + threadIdx.x; e < end; e += blockDim.x) {
    int pos = atomicAdd(&cur[rel[e]], 1);  // LDS atomic, cheap
    perm[pos] = e;
  }
}

// ---- destination CSR (rp by dst; col = perm-position of each msg) --------

__global__ void zero_cnt_kernel(int* __restrict__ cnt, int n) {
  int i = blockIdx.x * blockDim.x + threadIdx.x;
  if (i < n) cnt[i] = 0;
}

// cnt[0..N) = fwd (key dep), cnt[N..2N) = rev (key gov); 30k bins: low contention
__global__ void hist_dst_kernel(const int* __restrict__ dep,
                                const int* __restrict__ gov,
                                int* __restrict__ cnt) {
  int e = blockIdx.x * blockDim.x + threadIdx.x;
  if (e < N_EDGES) {
    atomicAdd(&cnt[dep[e]], 1);
    atomicAdd(&cnt[N_NODES + gov[e]], 1);
  }
}

__global__ void scanA_kernel(const int* __restrict__ cnt,
                             int* __restrict__ tmp, int* __restrict__ sums) {
  __shared__ int s[SCAN_CHUNK];
  int d = blockIdx.y, b = blockIdx.x, t = threadIdx.x;
  int i = b * SCAN_CHUNK + t;
  int v = (i < N_NODES) ? cnt[d * N_NODES + i] : 0;
  s[t] = v;
  __syncthreads();
  for (int off = 1; off < SCAN_CHUNK; off <<= 1) {
    int add = (t >= off) ? s[t - off] : 0;
    __syncthreads();
    s[t] += add;
    __syncthreads();
  }
  if (i < N_NODES) tmp[d * N_NODES + i] = s[t] - v;  // exclusive
  if (t == SCAN_CHUNK - 1) sums[d * SCAN_BLOCKS + b] = s[t];
}

__global__ void scanB_kernel(const int* __restrict__ sums,
                             int* __restrict__ chunk_off, int* __restrict__ rp) {
  __shared__ int s[128];
  int d = blockIdx.x, t = threadIdx.x;
  int v = (t < SCAN_BLOCKS) ? sums[d * SCAN_BLOCKS + t] : 0;
  s[t] = v;
  __syncthreads();
  for (int off = 1; off < 128; off <<= 1) {
    int add = (t >= off) ? s[t - off] : 0;
    __syncthreads();
    s[t] += add;
    __syncthreads();
  }
  if (t < SCAN_BLOCKS) chunk_off[d * SCAN_BLOCKS + t] = s[t] - v;
  if (t == 127) rp[d * (N_NODES + 1) + N_NODES] = s[127];
}

__global__ void scanC_kernel(const int* __restrict__ tmp,
                             const int* __restrict__ chunk_off,
                             int* __restrict__ rp, int* __restrict__ cursor) {
  int d = blockIdx.y;
  int i = blockIdx.x * SCAN_CHUNK + threadIdx.x;
  if (i < N_NODES) {
    int v = tmp[d * N_NODES + i] + chunk_off[d * SCAN_BLOCKS + blockIdx.x];
    rp[d * (N_NODES + 1) + i] = v;
    cursor[d * N_NODES + i] = v;
  }
}

// col lists hold msg ROW indices (= perm positions p), keyed by destination
__global__ void colidx_kernel(const int* __restrict__ perm,
                              const int* __restrict__ dep,
                              const int* __restrict__ gov,
                              int* __restrict__ cursor,
                              int* __restrict__ colf,
                              int* __restrict__ colr) {
  int p = blockIdx.x * blockDim.x + threadIdx.x;
  if (p < N_EDGES) {
    int e = perm[p];
    colf[atomicAdd(&cursor[dep[e]], 1)] = p;             // fwd msg p -> dep
    colr[atomicAdd(&cursor[N_NODES + gov[e]], 1)] = p;   // rev msg p -> gov
  }
}

// ---- self GEMM: out = x @ W_self + b_self (plain stores, runs first) -----

__global__ void self_gemm_kernel(const unsigned short* __restrict__ xbf,
                                 const unsigned short* __restrict__ wt_self,
                                 const float* __restrict__ b_self,
                                 float* __restrict__ out) {
  const int tid = threadIdx.x;
  const int wave = tid >> 6, lane = tid & 63;
  const int lm = lane & 15, q = lane >> 4;
  const int nb = wave * 64;
  const int row0 = blockIdx.x * 64;

  const unsigned short* xr[4];
  #pragma unroll
  for (int mi = 0; mi < 4; ++mi) {
    int r = row0 + mi * 16 + lm;
    int rc = r < N_NODES ? r : N_NODES - 1;
    xr[mi] = xbf + (size_t)rc * DIM + q * 8;
  }
  const unsigned short* wr[4];
  #pragma unroll
  for (int ni = 0; ni < 4; ++ni)
    wr[ni] = wt_self + (size_t)(nb + ni * 16 + lm) * DIM + q * 8;

  f32x4 acc[4][4];
  #pragma unroll
  for (int mi = 0; mi < 4; ++mi)
    #pragma unroll
    for (int ni = 0; ni < 4; ++ni)
      acc[mi][ni] = (f32x4){0.f, 0.f, 0.f, 0.f};

  #pragma unroll
  for (int k0 = 0; k0 < DIM; k0 += 32) {
    bf16x8 a[4], b[4];
    #pragma unroll
    for (int mi = 0; mi < 4; ++mi) a[mi] = *reinterpret_cast<const bf16x8*>(xr[mi] + k0);
    #pragma unroll
    for (int ni = 0; ni < 4; ++ni) b[ni] = *reinterpret_cast<const bf16x8*>(wr[ni] + k0);
    #pragma unroll
    for (int mi = 0; mi < 4; ++mi)
      #pragma unroll
      for (int ni = 0; ni < 4; ++ni)
        acc[mi][ni] = __builtin_amdgcn_mfma_f32_16x16x32_bf16(a[mi], b[ni], acc[mi][ni], 0, 0, 0);
  }

  float bias[4];
  #pragma unroll
  for (int ni = 0; ni < 4; ++ni) bias[ni] = b_self[nb + ni * 16 + lm];

  #pragma unroll
  for (int mi = 0; mi < 4; ++mi) {
    #pragma unroll
    for (int reg = 0; reg < 4; ++reg) {
      int row = row0 + mi * 16 + q * 4 + reg;  // C/D: row = quad*4 + reg
      if (row < N_NODES) {
        #pragma unroll
        for (int ni = 0; ni < 4; ++ni)
          out[(size_t)row * DIM + nb + ni * 16 + lm] = acc[mi][ni][reg] + bias[ni];
      }
    }
  }
}

// ---- phase 1: rel-bucketed GEMM -> bf16 msg row p (STREAMING stores) -----
// msg row p = perm position. Column order in each 64-col block: elem nb+lm*4+ni
// holds col nb+ni*16+lm; reducer inverts with index math.

__global__ void edge_gemm_p1_kernel(const unsigned short* __restrict__ xbf,
                                    const unsigned short* __restrict__ wt,
                                    const float* __restrict__ bias_all,
                                    const int* __restrict__ perm,
                                    const int* __restrict__ rel_start,
                                    const int* __restrict__ src_idx,
                                    unsigned short* __restrict__ msg,
                                    int wt_base) {
  const int r = blockIdx.y;
  const int beg = rel_start[r];
  const int cnt = rel_start[r + 1] - beg;
  const int ntiles = (cnt + 63) >> 6;

  const int tid = threadIdx.x;
  const int wave = tid >> 6, lane = tid & 63;
  const int lm = lane & 15, q = lane >> 4;
  const int nb = wave * 64;

  __shared__ int s_src[64];

  const unsigned short* wr[4];
  #pragma unroll
  for (int ni = 0; ni < 4; ++ni)
    wr[ni] = wt + (size_t)(wt_base + r) * DIM * DIM + (size_t)(nb + ni * 16 + lm) * DIM + q * 8;

  const float* bptr = bias_all + r * DIM;
  float bias[4];
  #pragma unroll
  for (int ni = 0; ni < 4; ++ni) bias[ni] = bptr[nb + ni * 16 + lm];

  for (int t = blockIdx.x; t < ntiles; t += gridDim.x) {
    const int tile0 = t << 6;
    const int rows_valid = min(64, cnt - tile0);

    if (tid < 64) {
      int s = 0;
      if (tid < rows_valid) s = src_idx[perm[beg + tile0 + tid]];
      s_src[tid] = s;
    }
    __syncthreads();

    const unsigned short* xr[4];
    #pragma unroll
    for (int mi = 0; mi < 4; ++mi)
      xr[mi] = xbf + (size_t)s_src[mi * 16 + lm] * DIM + q * 8;

    f32x4 acc[4][4];
    #pragma unroll
    for (int mi = 0; mi < 4; ++mi)
      #pragma unroll
      for (int ni = 0; ni < 4; ++ni)
        acc[mi][ni] = (f32x4){0.f, 0.f, 0.f, 0.f};

    #pragma unroll
    for (int k0 = 0; k0 < DIM; k0 += 32) {
      bf16x8 a[4], b[4];
      #pragma unroll
      for (int mi = 0; mi < 4; ++mi) a[mi] = *reinterpret_cast<const bf16x8*>(xr[mi] + k0);
      #pragma unroll
      for (int ni = 0; ni < 4; ++ni) b[ni] = *reinterpret_cast<const bf16x8*>(wr[ni] + k0);
      #pragma unroll
      for (int mi = 0; mi < 4; ++mi)
        #pragma unroll
        for (int ni = 0; ni < 4; ++ni)
          acc[mi][ni] = __builtin_amdgcn_mfma_f32_16x16x32_bf16(a[mi], b[ni], acc[mi][ni], 0, 0, 0);
    }

    // streaming store: block covers [ (beg+tile0)*DIM , +64*DIM ) contiguous
    #pragma unroll
    for (int mi = 0; mi < 4; ++mi) {
      #pragma unroll
      for (int reg = 0; reg < 4; ++reg) {
        int row = mi * 16 + q * 4 + reg;
        if (row < rows_valid) {
          unsigned int p0 = ((unsigned int)f2bf(acc[mi][1][reg] + bias[1]) << 16) |
                            f2bf(acc[mi][0][reg] + bias[0]);
          unsigned int p1 = ((unsigned int)f2bf(acc[mi][3][reg] + bias[3]) << 16) |
                            f2bf(acc[mi][2][reg] + bias[2]);
          uint2 u; u.x = p0; u.y = p1;
          *reinterpret_cast<uint2*>(msg + (size_t)(beg + tile0 + row) * DIM + nb + lm * 4) = u;
        }
      }
    }
    __syncthreads();
  }
}

// ---- phase 2: CSR gather-sum of bf16 msgs, out += ------------------------

__global__ void reduce_kernel(const unsigned short* __restrict__ msg,
                              const int* __restrict__ rp,
                              const int* __restrict__ col,
                              float* __restrict__ out) {
  int n = blockIdx.x, t = threadIdx.x;
  int beg = rp[n], end = rp[n + 1];
  if (end <= beg) return;
  int lmv = t & 15, niv = (t >> 4) & 3, b64 = t >> 6;
  int pos = b64 * 64 + lmv * 4 + niv;  // inverse column permutation
  float acc = 0.f;
  for (int j = beg; j < end; ++j) {
    int row = col[j];
    unsigned int u = msg[(size_t)row * DIM + pos];
    union { unsigned int u; float f; } c; c.u = u << 16;
    acc += c.f;
  }
  out[(size_t)n * DIM + t] += acc;
}

// ---- fallback: single-phase atomic scatter (if ws too small) -------------

__global__ void edge_gemm_atomic_kernel(const unsigned short* __restrict__ xbf,
                                        const unsigned short* __restrict__ wt,
                                        const float* __restrict__ b_fwd,
                                        const float* __restrict__ b_rev,
                                        const int* __restrict__ perm,
                                        const int* __restrict__ rel_start,
                                        const int* __restrict__ dep,
                                        const int* __restrict__ gov,
                                        float* __restrict__ out) {
  const int bucket = blockIdx.y;
  const int r = bucket % N_REL;
  const bool fwd = bucket < N_REL;
  const int beg = rel_start[r];
  const int cnt = rel_start[r + 1] - beg;
  const int ntiles = (cnt + 63) >> 6;

  const int tid = threadIdx.x;
  const int wave = tid >> 6, lane = tid & 63;
  const int lm = lane & 15, q = lane >> 4;
  const int nb = wave * 64;

  __shared__ int s_src[64], s_dst[64];

  const unsigned short* wr[4];
  #pragma unroll
  for (int ni = 0; ni < 4; ++ni)
    wr[ni] = wt + (size_t)bucket * DIM * DIM + (size_t)(nb + ni * 16 + lm) * DIM + q * 8;

  const float* bptr = (fwd ? b_fwd : b_rev) + r * DIM;
  float bias[4];
  #pragma unroll
  for (int ni = 0; ni < 4; ++ni) bias[ni] = bptr[nb + ni * 16 + lm];

  for (int t = blockIdx.x; t < ntiles; t += gridDim.x) {
    const int tile0 = t << 6;
    const int rows_valid = min(64, cnt - tile0);

    if (tid < 64) {
      int s = 0, d = -1;
      if (tid < rows_valid) {
        int e = perm[beg + tile0 + tid];
        int gv = gov[e], dp = dep[e];
        s = fwd ? gv : dp;
        d = fwd ? dp : gv;
      }
      s_src[tid] = s;
      s_dst[tid] = d;
    }
    __syncthreads();

    const unsigned short* xr[4];
    #pragma unroll
    for (int mi = 0; mi < 4; ++mi)
      xr[mi] = xbf + (size_t)s_src[mi * 16 + lm] * DIM + q * 8;

    f32x4 acc[4][4];
    #pragma unroll
    for (int mi = 0; mi < 4; ++mi)
      #pragma unroll
      for (int ni = 0; ni < 4; ++ni)
        acc[mi][ni] = (f32x4){0.f, 0.f, 0.f, 0.f};

    #pragma unroll
    for (int k0 = 0; k0 < DIM; k0 += 32) {
      bf16x8 a[4], b[4];
      #pragma unroll
      for (int mi = 0; mi < 4; ++mi) a[mi] = *reinterpret_cast<const bf16x8*>(xr[mi] + k0);
      #pragma unroll
      for (int ni = 0; ni < 4; ++ni) b[ni] = *reinterpret_cast<const bf16x8*>(wr[ni] + k0);
      #pragma unroll
      for (int mi = 0; mi < 4; ++mi)
        #pragma unroll
        for (int ni = 0; ni < 4; ++ni)
          acc[mi][ni] = __builtin_amdgcn_mfma_f32_16x16x32_bf16(a[mi], b[ni], acc[mi][ni], 0, 0, 0);
    }

    #pragma unroll
    for (int mi = 0; mi < 4; ++mi) {
      #pragma unroll
      for (int reg = 0; reg < 4; ++reg) {
        int row = mi * 16 + q * 4 + reg;
        if (row < rows_valid) {
          int dst = s_dst[row];
          float* op = out + (size_t)dst * DIM + nb + lm;
          #pragma unroll
          for (int ni = 0; ni < 4; ++ni)
            atomicAdd(op + ni * 16, acc[mi][ni][reg] + bias[ni]);
        }
      }
    }
    __syncthreads();
  }
}

// ---- launch --------------------------------------------------------------

extern "C" void kernel_launch(void* const* d_in, const int* in_sizes, int n_in,
                              void* d_out, int out_size, void* d_ws, size_t ws_size,
                              hipStream_t stream) {
  const float* x      = (const float*)d_in[0];
  const float* W_self = (const float*)d_in[1];
  const float* b_self = (const float*)d_in[2];
  const float* W_fwd  = (const float*)d_in[3];
  const float* b_fwd  = (const float*)d_in[4];
  const float* W_rev  = (const float*)d_in[5];
  const float* b_rev  = (const float*)d_in[6];
  const int* dep = (const int*)d_in[7];
  const int* rel = (const int*)d_in[8];
  const int* gov = (const int*)d_in[9];
  float* out = (float*)d_out;

  char* base = (char*)d_ws;
  size_t off = 0;
  auto alloc = [&](size_t bytes) -> char* {
    char* p = base + off;
    off = (off + bytes + 15) & ~(size_t)15;
    return p;
  };

  unsigned short* xbf = (unsigned short*)alloc((size_t)N_NODES * DIM * 2);
  unsigned short* wt  = (unsigned short*)alloc((size_t)21 * DIM * DIM * 2);
  int* perm          = (int*)alloc((size_t)N_EDGES * 4);
  int* rel_start     = (int*)alloc(16 * 4);
  int* block_counts  = (int*)alloc(SORT_BLOCKS * N_REL * 4);
  int* block_offset  = (int*)alloc(SORT_BLOCKS * N_REL * 4);
  // two-phase extras
  int* cnt       = (int*)alloc((size_t)2 * N_NODES * 4);
  int* tmp       = (int*)alloc((size_t)2 * N_NODES * 4);
  int* sums      = (int*)alloc((size_t)2 * SCAN_BLOCKS * 4);
  int* chunk_off = (int*)alloc((size_t)2 * SCAN_BLOCKS * 4);
  int* rp        = (int*)alloc((size_t)2 * (N_NODES + 1) * 4);
  int* cursor    = (int*)alloc((size_t)2 * N_NODES * 4);
  int* colf      = (int*)alloc((size_t)N_EDGES * 4);
  int* colr      = (int*)alloc((size_t)N_EDGES * 4);
  unsigned short* msg = (unsigned short*)alloc((size_t)N_EDGES * DIM * 2);  // 76.8 MB
  const bool two_phase = (off <= ws_size);

  conv_x_kernel<<<N_NODES * DIM / 4 / 256, 256, 0, stream>>>(x, xbf);
  conv_w_kernel<<<21 * DIM * DIM / 256, 256, 0, stream>>>(W_fwd, W_rev, W_self, wt);
  blockhist_kernel<<<SORT_BLOCKS, 256, 0, stream>>>(rel, block_counts);
  scan_rel_kernel<<<1, 64, 0, stream>>>(block_counts, rel_start, block_offset);
  scatter2_kernel<<<SORT_BLOCKS, 256, 0, stream>>>(rel, block_offset, perm);
  // self GEMM first: plain stores initialize all of out (stream-ordered
  // ahead of any accumulation)
  self_gemm_kernel<<<(N_NODES + 63) / 64, 256, 0, stream>>>(
      xbf, wt + (size_t)20 * DIM * DIM, b_self, out);

  if (two_phase) {
    zero_cnt_kernel<<<(2 * N_NODES + 255) / 256, 256, 0, stream>>>(cnt, 2 * N_NODES);
    hist_dst_kernel<<<(N_EDGES + 255) / 256, 256, 0, stream>>>(dep, gov, cnt);
    scanA_kernel<<<dim3(SCAN_BLOCKS, 2), SCAN_CHUNK, 0, stream>>>(cnt, tmp, sums);
    scanB_kernel<<<2, 128, 0, stream>>>(sums, chunk_off, rp);
    scanC_kernel<<<dim3(SCAN_BLOCKS, 2), SCAN_CHUNK, 0, stream>>>(tmp, chunk_off, rp, cursor);
    colidx_kernel<<<(N_EDGES + 255) / 256, 256, 0, stream>>>(perm, dep, gov, cursor, colf, colr);

    // forward: msg[p] = W_fwd[rel] @ x[gov] + b_fwd, p = perm position
    edge_gemm_p1_kernel<<<dim3(240, N_REL), 256, 0, stream>>>(
        xbf, wt, b_fwd, perm, rel_start, gov, msg, 0);
    reduce_kernel<<<N_NODES, 256, 0, stream>>>(msg, rp, colf, out);
    // reverse: msg[p] = W_rev[rel] @ x[dep] + b_rev (reuses msg buffer)
    edge_gemm_p1_kernel<<<dim3(240, N_REL), 256, 0, stream>>>(
        xbf, wt, b_rev, perm, rel_start, dep, msg, N_REL);
    reduce_kernel<<<N_NODES, 256, 0, stream>>>(msg, rp + (N_NODES + 1), colr, out);
  } else {
    edge_gemm_atomic_kernel<<<dim3(260, 20), 256, 0, stream>>>(
        xbf, wt, b_fwd, b_rev, perm, rel_start, dep, gov, out);
  }
}

// Round 5
// 619.547 us; speedup vs baseline: 1.0799x; 1.0799x over previous
//
#include <hip/hip_runtime.h>

#define N_NODES 30000
#define N_EDGES 150000
#define N_REL 10
#define DIM 256

#define SORT_BLOCKS 120
#define SORT_CHUNK ((N_EDGES + SORT_BLOCKS - 1) / SORT_BLOCKS)  // 1250

#define SCAN_CHUNK 256
#define SCAN_BLOCKS ((N_NODES + SCAN_CHUNK - 1) / SCAN_CHUNK)   // 118

// LDS A-tile row stride: 280 shorts = 560 B (16B-aligned, breaks pow2 banks)
#define A_STRIDE 280

typedef __attribute__((ext_vector_type(8))) short bf16x8;
typedef __attribute__((ext_vector_type(4))) float f32x4;

__device__ __forceinline__ unsigned short f2bf(float f) {
  union { float f; unsigned int u; } v; v.f = f;
  unsigned int u = v.u;
  unsigned int r = u + 0x7fffu + ((u >> 16) & 1u);  // RNE
  return (unsigned short)(r >> 16);
}

// ---- preprocessing -------------------------------------------------------

__global__ void conv_x_kernel(const float* __restrict__ x,
                              unsigned short* __restrict__ xbf) {
  int idx = blockIdx.x * blockDim.x + threadIdx.x;  // one float4 each, exact grid
  float4 v = reinterpret_cast<const float4*>(x)[idx];
  ushort4 o;
  o.x = f2bf(v.x); o.y = f2bf(v.y); o.z = f2bf(v.z); o.w = f2bf(v.w);
  reinterpret_cast<ushort4*>(xbf)[idx] = o;
}

// wt[b][o][i] = W_b[i][o] (bf16), buckets: 0..9 fwd, 10..19 rev, 20 self
__global__ void conv_w_kernel(const float* __restrict__ Wf,
                              const float* __restrict__ Wr,
                              const float* __restrict__ Ws,
                              unsigned short* __restrict__ wt) {
  int idx = blockIdx.x * blockDim.x + threadIdx.x;  // exact grid 21*65536
  int b = idx >> 16;
  int t = idx & 65535;
  int o = t >> 8, i = t & 255;
  const float* src = (b < N_REL) ? (Wf + (size_t)b * 65536)
                   : (b < 2 * N_REL) ? (Wr + (size_t)(b - N_REL) * 65536)
                   : Ws;
  wt[idx] = f2bf(src[i * 256 + o]);
}

// ---- counting sort by relation (block-local hist, no global atomics) -----

__global__ void blockhist_kernel(const int* __restrict__ rel,
                                 int* __restrict__ block_counts) {
  __shared__ int h[N_REL];
  if (threadIdx.x < N_REL) h[threadIdx.x] = 0;
  __syncthreads();
  int beg = blockIdx.x * SORT_CHUNK;
  int end = min(beg + SORT_CHUNK, N_EDGES);
  for (int e = beg + threadIdx.x; e < end; e += blockDim.x)
    atomicAdd(&h[rel[e]], 1);
  __syncthreads();
  if (threadIdx.x < N_REL)
    block_counts[blockIdx.x * N_REL + threadIdx.x] = h[threadIdx.x];
}

__global__ void scan_rel_kernel(const int* __restrict__ block_counts,
                                int* __restrict__ rel_start,
                                int* __restrict__ block_offset) {
  __shared__ int tot[N_REL];
  int r = threadIdx.x;
  if (r < N_REL) {
    int s = 0;
    for (int b = 0; b < SORT_BLOCKS; ++b) s += block_counts[b * N_REL + r];
    tot[r] = s;
  }
  __syncthreads();
  if (threadIdx.x == 0) {
    int s = 0;
    for (int i = 0; i < N_REL; ++i) { rel_start[i] = s; s += tot[i]; }
    rel_start[N_REL] = s;
  }
  __syncthreads();
  if (r < N_REL) {
    int run = rel_start[r];
    for (int b = 0; b < SORT_BLOCKS; ++b) {
      block_offset[b * N_REL + r] = run;
      run += block_counts[b * N_REL + r];
    }
  }
}

__global__ void scatter2_kernel(const int* __restrict__ rel,
                                const int* __restrict__ block_offset,
                                int* __restrict__ perm) {
  __shared__ int cur[N_REL];
  if (threadIdx.x < N_REL)
    cur[threadIdx.x] = block_offset[blockIdx.x * N_REL + threadIdx.x];
  __syncthreads();
  int beg = blockIdx.x * SORT_CHUNK;
  int end = min(beg + SORT_CHUNK, N_EDGES);
  for (int e = beg + threadIdx.x; e < end; e += blockDim.x) {
    int pos = atomicAdd(&cur[rel[e]], 1);  // LDS atomic, cheap
    perm[pos] = e;
  }
}

// ---- destination CSR (rp by dst; col = perm-position of each msg) --------

__global__ void zero_cnt_kernel(int* __restrict__ cnt, int n) {
  int i = blockIdx.x * blockDim.x + threadIdx.x;
  if (i < n) cnt[i] = 0;
}

__global__ void hist_dst_kernel(const int* __restrict__ dep,
                                const int* __restrict__ gov,
                                int* __restrict__ cnt) {
  int e = blockIdx.x * blockDim.x + threadIdx.x;
  if (e < N_EDGES) {
    atomicAdd(&cnt[dep[e]], 1);
    atomicAdd(&cnt[N_NODES + gov[e]], 1);
  }
}

__global__ void scanA_kernel(const int* __restrict__ cnt,
                             int* __restrict__ tmp, int* __restrict__ sums) {
  __shared__ int s[SCAN_CHUNK];
  int d = blockIdx.y, b = blockIdx.x, t = threadIdx.x;
  int i = b * SCAN_CHUNK + t;
  int v = (i < N_NODES) ? cnt[d * N_NODES + i] : 0;
  s[t] = v;
  __syncthreads();
  for (int off = 1; off < SCAN_CHUNK; off <<= 1) {
    int add = (t >= off) ? s[t - off] : 0;
    __syncthreads();
    s[t] += add;
    __syncthreads();
  }
  if (i < N_NODES) tmp[d * N_NODES + i] = s[t] - v;  // exclusive
  if (t == SCAN_CHUNK - 1) sums[d * SCAN_BLOCKS + b] = s[t];
}

__global__ void scanB_kernel(const int* __restrict__ sums,
                             int* __restrict__ chunk_off, int* __restrict__ rp) {
  __shared__ int s[128];
  int d = blockIdx.x, t = threadIdx.x;
  int v = (t < SCAN_BLOCKS) ? sums[d * SCAN_BLOCKS + t] : 0;
  s[t] = v;
  __syncthreads();
  for (int off = 1; off < 128; off <<= 1) {
    int add = (t >= off) ? s[t - off] : 0;
    __syncthreads();
    s[t] += add;
    __syncthreads();
  }
  if (t < SCAN_BLOCKS) chunk_off[d * SCAN_BLOCKS + t] = s[t] - v;
  if (t == 127) rp[d * (N_NODES + 1) + N_NODES] = s[127];
}

__global__ void scanC_kernel(const int* __restrict__ tmp,
                             const int* __restrict__ chunk_off,
                             int* __restrict__ rp, int* __restrict__ cursor) {
  int d = blockIdx.y;
  int i = blockIdx.x * SCAN_CHUNK + threadIdx.x;
  if (i < N_NODES) {
    int v = tmp[d * N_NODES + i] + chunk_off[d * SCAN_BLOCKS + blockIdx.x];
    rp[d * (N_NODES + 1) + i] = v;
    cursor[d * N_NODES + i] = v;
  }
}

// col lists hold msg ROW indices (= perm positions p), keyed by destination
__global__ void colidx_kernel(const int* __restrict__ perm,
                              const int* __restrict__ dep,
                              const int* __restrict__ gov,
                              int* __restrict__ cursor,
                              int* __restrict__ colf,
                              int* __restrict__ colr) {
  int p = blockIdx.x * blockDim.x + threadIdx.x;
  if (p < N_EDGES) {
    int e = perm[p];
    colf[atomicAdd(&cursor[dep[e]], 1)] = p;             // fwd msg p -> dep
    colr[atomicAdd(&cursor[N_NODES + gov[e]], 1)] = p;   // rev msg p -> gov
  }
}

// ---- self GEMM: out = x @ W_self + b_self (plain stores, runs first) -----

__global__ void self_gemm_kernel(const unsigned short* __restrict__ xbf,
                                 const unsigned short* __restrict__ wt_self,
                                 const float* __restrict__ b_self,
                                 float* __restrict__ out) {
  const int tid = threadIdx.x;
  const int wave = tid >> 6, lane = tid & 63;
  const int lm = lane & 15, q = lane >> 4;
  const int nb = wave * 64;
  const int row0 = blockIdx.x * 64;

  const unsigned short* xr[4];
  #pragma unroll
  for (int mi = 0; mi < 4; ++mi) {
    int r = row0 + mi * 16 + lm;
    int rc = r < N_NODES ? r : N_NODES - 1;
    xr[mi] = xbf + (size_t)rc * DIM + q * 8;
  }
  const unsigned short* wr[4];
  #pragma unroll
  for (int ni = 0; ni < 4; ++ni)
    wr[ni] = wt_self + (size_t)(nb + ni * 16 + lm) * DIM + q * 8;

  f32x4 acc[4][4];
  #pragma unroll
  for (int mi = 0; mi < 4; ++mi)
    #pragma unroll
    for (int ni = 0; ni < 4; ++ni)
      acc[mi][ni] = (f32x4){0.f, 0.f, 0.f, 0.f};

  #pragma unroll
  for (int k0 = 0; k0 < DIM; k0 += 32) {
    bf16x8 a[4], b[4];
    #pragma unroll
    for (int mi = 0; mi < 4; ++mi) a[mi] = *reinterpret_cast<const bf16x8*>(xr[mi] + k0);
    #pragma unroll
    for (int ni = 0; ni < 4; ++ni) b[ni] = *reinterpret_cast<const bf16x8*>(wr[ni] + k0);
    #pragma unroll
    for (int mi = 0; mi < 4; ++mi)
      #pragma unroll
      for (int ni = 0; ni < 4; ++ni)
        acc[mi][ni] = __builtin_amdgcn_mfma_f32_16x16x32_bf16(a[mi], b[ni], acc[mi][ni], 0, 0, 0);
  }

  float bias[4];
  #pragma unroll
  for (int ni = 0; ni < 4; ++ni) bias[ni] = b_self[nb + ni * 16 + lm];

  #pragma unroll
  for (int mi = 0; mi < 4; ++mi) {
    #pragma unroll
    for (int reg = 0; reg < 4; ++reg) {
      int row = row0 + mi * 16 + q * 4 + reg;  // C/D: row = quad*4 + reg
      if (row < N_NODES) {
        #pragma unroll
        for (int ni = 0; ni < 4; ++ni)
          out[(size_t)row * DIM + nb + ni * 16 + lm] = acc[mi][ni][reg] + bias[ni];
      }
    }
  }
}

// ---- phase 1: rel-bucketed GEMM, LDS-staged A, linear bulk stores --------
// msg row p = perm position; msg row layout = natural columns (bf16).

__global__ void edge_gemm_p1_kernel(const unsigned short* __restrict__ xbf,
                                    const unsigned short* __restrict__ wt,
                                    const float* __restrict__ bias_all,
                                    const int* __restrict__ perm,
                                    const int* __restrict__ rel_start,
                                    const int* __restrict__ src_idx,
                                    unsigned short* __restrict__ msg,
                                    int wt_base) {
  const int r = blockIdx.y;
  const int beg = rel_start[r];
  const int cnt = rel_start[r + 1] - beg;
  const int ntiles = (cnt + 63) >> 6;

  const int tid = threadIdx.x;
  const int wave = tid >> 6, lane = tid & 63;
  const int lm = lane & 15, q = lane >> 4;
  const int nb = wave * 64;

  __shared__ int s_src[64];
  __shared__ unsigned short sA[64 * A_STRIDE];  // 35840 B; reused by epilogue

  const unsigned short* wr[4];
  #pragma unroll
  for (int ni = 0; ni < 4; ++ni)
    wr[ni] = wt + (size_t)(wt_base + r) * DIM * DIM + (size_t)(nb + ni * 16 + lm) * DIM + q * 8;

  const float* bptr = bias_all + r * DIM;
  float bias[4];
  #pragma unroll
  for (int ni = 0; ni < 4; ++ni) bias[ni] = bptr[nb + ni * 16 + lm];

  for (int t = blockIdx.x; t < ntiles; t += gridDim.x) {
    const int tile0 = t << 6;
    const int rows_valid = min(64, cnt - tile0);

    if (tid < 64) {
      int s = 0;
      if (tid < rows_valid) s = src_idx[perm[beg + tile0 + tid]];
      s_src[tid] = s;
    }
    __syncthreads();

    // stage 64 gathered x rows into LDS (each row fetched exactly once)
    // wave handles rows [wave*16, wave*16+16); 2 rows per iter (32 lanes/row)
    {
      int half = lane >> 5;        // 0 or 1
      int lcol = lane & 31;        // 16B chunk index within row
      #pragma unroll
      for (int i = 0; i < 8; ++i) {
        int row = wave * 16 + i * 2 + half;
        const uint4* gp = reinterpret_cast<const uint4*>(
            xbf + (size_t)s_src[row] * DIM + lcol * 8);
        uint4 v = *gp;
        *reinterpret_cast<uint4*>(sA + row * A_STRIDE + lcol * 8) = v;
      }
    }
    __syncthreads();

    f32x4 acc[4][4];
    #pragma unroll
    for (int mi = 0; mi < 4; ++mi)
      #pragma unroll
      for (int ni = 0; ni < 4; ++ni)
        acc[mi][ni] = (f32x4){0.f, 0.f, 0.f, 0.f};

    #pragma unroll
    for (int k0 = 0; k0 < DIM; k0 += 32) {
      bf16x8 a[4], b[4];
      #pragma unroll
      for (int mi = 0; mi < 4; ++mi)
        a[mi] = *reinterpret_cast<const bf16x8*>(sA + (mi * 16 + lm) * A_STRIDE + k0 + q * 8);
      #pragma unroll
      for (int ni = 0; ni < 4; ++ni) b[ni] = *reinterpret_cast<const bf16x8*>(wr[ni] + k0);
      #pragma unroll
      for (int mi = 0; mi < 4; ++mi)
        #pragma unroll
        for (int ni = 0; ni < 4; ++ni)
          acc[mi][ni] = __builtin_amdgcn_mfma_f32_16x16x32_bf16(a[mi], b[ni], acc[mi][ni], 0, 0, 0);
    }
    __syncthreads();  // k-loop done; sA free for epilogue transpose

    // transpose acc to natural [row][col] bf16 layout in LDS
    #pragma unroll
    for (int mi = 0; mi < 4; ++mi)
      #pragma unroll
      for (int reg = 0; reg < 4; ++reg) {
        int row = mi * 16 + q * 4 + reg;
        #pragma unroll
        for (int ni = 0; ni < 4; ++ni)
          sA[row * DIM + nb + ni * 16 + lm] = f2bf(acc[mi][ni][reg] + bias[ni]);
      }
    __syncthreads();

    // bulk copy LDS -> msg: 8 iters x 256 threads x 16B = 32 KB linear
    unsigned short* mbase = msg + (size_t)(beg + tile0) * DIM;
    #pragma unroll
    for (int it = 0; it < 8; ++it) {
      int elem = it * 2048 + tid * 8;
      if ((elem >> 8) < rows_valid) {
        uint4 v = *reinterpret_cast<const uint4*>(sA + elem);
        *reinterpret_cast<uint4*>(mbase + elem) = v;
      }
    }
    __syncthreads();
  }
}

// ---- phase 2: CSR gather-sum of bf16 msgs (natural layout), out += -------

__global__ void reduce_kernel(const unsigned short* __restrict__ msg,
                              const int* __restrict__ rp,
                              const int* __restrict__ col,
                              float* __restrict__ out) {
  int n = blockIdx.x, t = threadIdx.x;
  int beg = rp[n], end = rp[n + 1];
  if (end <= beg) return;
  float acc = 0.f;
  for (int j = beg; j < end; ++j) {
    int row = col[j];
    unsigned int u = msg[(size_t)row * DIM + t];
    union { unsigned int u; float f; } c; c.u = u << 16;
    acc += c.f;
  }
  out[(size_t)n * DIM + t] += acc;
}

// ---- fallback: single-phase atomic scatter (if ws too small) -------------

__global__ void edge_gemm_atomic_kernel(const unsigned short* __restrict__ xbf,
                                        const unsigned short* __restrict__ wt,
                                        const float* __restrict__ b_fwd,
                                        const float* __restrict__ b_rev,
                                        const int* __restrict__ perm,
                                        const int* __restrict__ rel_start,
                                        const int* __restrict__ dep,
                                        const int* __restrict__ gov,
                                        float* __restrict__ out) {
  const int bucket = blockIdx.y;
  const int r = bucket % N_REL;
  const bool fwd = bucket < N_REL;
  const int beg = rel_start[r];
  const int cnt = rel_start[r + 1] - beg;
  const int ntiles = (cnt + 63) >> 6;

  const int tid = threadIdx.x;
  const int wave = tid >> 6, lane = tid & 63;
  const int lm = lane & 15, q = lane >> 4;
  const int nb = wave * 64;

  __shared__ int s_src[64], s_dst[64];

  const unsigned short* wr[4];
  #pragma unroll
  for (int ni = 0; ni < 4; ++ni)
    wr[ni] = wt + (size_t)bucket * DIM * DIM + (size_t)(nb + ni * 16 + lm) * DIM + q * 8;

  const float* bptr = (fwd ? b_fwd : b_rev) + r * DIM;
  float bias[4];
  #pragma unroll
  for (int ni = 0; ni < 4; ++ni) bias[ni] = bptr[nb + ni * 16 + lm];

  for (int t = blockIdx.x; t < ntiles; t += gridDim.x) {
    const int tile0 = t << 6;
    const int rows_valid = min(64, cnt - tile0);

    if (tid < 64) {
      int s = 0, d = -1;
      if (tid < rows_valid) {
        int e = perm[beg + tile0 + tid];
        int gv = gov[e], dp = dep[e];
        s = fwd ? gv : dp;
        d = fwd ? dp : gv;
      }
      s_src[tid] = s;
      s_dst[tid] = d;
    }
    __syncthreads();

    const unsigned short* xr[4];
    #pragma unroll
    for (int mi = 0; mi < 4; ++mi)
      xr[mi] = xbf + (size_t)s_src[mi * 16 + lm] * DIM + q * 8;

    f32x4 acc[4][4];
    #pragma unroll
    for (int mi = 0; mi < 4; ++mi)
      #pragma unroll
      for (int ni = 0; ni < 4; ++ni)
        acc[mi][ni] = (f32x4){0.f, 0.f, 0.f, 0.f};

    #pragma unroll
    for (int k0 = 0; k0 < DIM; k0 += 32) {
      bf16x8 a[4], b[4];
      #pragma unroll
      for (int mi = 0; mi < 4; ++mi) a[mi] = *reinterpret_cast<const bf16x8*>(xr[mi] + k0);
      #pragma unroll
      for (int ni = 0; ni < 4; ++ni) b[ni] = *reinterpret_cast<const bf16x8*>(wr[ni] + k0);
      #pragma unroll
      for (int mi = 0; mi < 4; ++mi)
        #pragma unroll
        for (int ni = 0; ni < 4; ++ni)
          acc[mi][ni] = __builtin_amdgcn_mfma_f32_16x16x32_bf16(a[mi], b[ni], acc[mi][ni], 0, 0, 0);
    }

    #pragma unroll
    for (int mi = 0; mi < 4; ++mi) {
      #pragma unroll
      for (int reg = 0; reg < 4; ++reg) {
        int row = mi * 16 + q * 4 + reg;
        if (row < rows_valid) {
          int dst = s_dst[row];
          float* op = out + (size_t)dst * DIM + nb + lm;
          #pragma unroll
          for (int ni = 0; ni < 4; ++ni)
            atomicAdd(op + ni * 16, acc[mi][ni][reg] + bias[ni]);
        }
      }
    }
    __syncthreads();
  }
}

// ---- launch --------------------------------------------------------------

extern "C" void kernel_launch(void* const* d_in, const int* in_sizes, int n_in,
                              void* d_out, int out_size, void* d_ws, size_t ws_size,
                              hipStream_t stream) {
  const float* x      = (const float*)d_in[0];
  const float* W_self = (const float*)d_in[1];
  const float* b_self = (const float*)d_in[2];
  const float* W_fwd  = (const float*)d_in[3];
  const float* b_fwd  = (const float*)d_in[4];
  const float* W_rev  = (const float*)d_in[5];
  const float* b_rev  = (const float*)d_in[6];
  const int* dep = (const int*)d_in[7];
  const int* rel = (const int*)d_in[8];
  const int* gov = (const int*)d_in[9];
  float* out = (float*)d_out;

  char* base = (char*)d_ws;
  size_t off = 0;
  auto alloc = [&](size_t bytes) -> char* {
    char* p = base + off;
    off = (off + bytes + 15) & ~(size_t)15;
    return p;
  };

  unsigned short* xbf = (unsigned short*)alloc((size_t)N_NODES * DIM * 2);
  unsigned short* wt  = (unsigned short*)alloc((size_t)21 * DIM * DIM * 2);
  int* perm          = (int*)alloc((size_t)N_EDGES * 4);
  int* rel_start     = (int*)alloc(16 * 4);
  int* block_counts  = (int*)alloc(SORT_BLOCKS * N_REL * 4);
  int* block_offset  = (int*)alloc(SORT_BLOCKS * N_REL * 4);
  // two-phase extras
  int* cnt       = (int*)alloc((size_t)2 * N_NODES * 4);
  int* tmp       = (int*)alloc((size_t)2 * N_NODES * 4);
  int* sums      = (int*)alloc((size_t)2 * SCAN_BLOCKS * 4);
  int* chunk_off = (int*)alloc((size_t)2 * SCAN_BLOCKS * 4);
  int* rp        = (int*)alloc((size_t)2 * (N_NODES + 1) * 4);
  int* cursor    = (int*)alloc((size_t)2 * N_NODES * 4);
  int* colf      = (int*)alloc((size_t)N_EDGES * 4);
  int* colr      = (int*)alloc((size_t)N_EDGES * 4);
  unsigned short* msg = (unsigned short*)alloc((size_t)N_EDGES * DIM * 2);  // 76.8 MB
  const bool two_phase = (off <= ws_size);

  conv_x_kernel<<<N_NODES * DIM / 4 / 256, 256, 0, stream>>>(x, xbf);
  conv_w_kernel<<<21 * DIM * DIM / 256, 256, 0, stream>>>(W_fwd, W_rev, W_self, wt);
  blockhist_kernel<<<SORT_BLOCKS, 256, 0, stream>>>(rel, block_counts);
  scan_rel_kernel<<<1, 64, 0, stream>>>(block_counts, rel_start, block_offset);
  scatter2_kernel<<<SORT_BLOCKS, 256, 0, stream>>>(rel, block_offset, perm);
  // self GEMM first: plain stores initialize all of out (stream-ordered
  // ahead of any accumulation)
  self_gemm_kernel<<<(N_NODES + 63) / 64, 256, 0, stream>>>(
      xbf, wt + (size_t)20 * DIM * DIM, b_self, out);

  if (two_phase) {
    zero_cnt_kernel<<<(2 * N_NODES + 255) / 256, 256, 0, stream>>>(cnt, 2 * N_NODES);
    hist_dst_kernel<<<(N_EDGES + 255) / 256, 256, 0, stream>>>(dep, gov, cnt);
    scanA_kernel<<<dim3(SCAN_BLOCKS, 2), SCAN_CHUNK, 0, stream>>>(cnt, tmp, sums);
    scanB_kernel<<<2, 128, 0, stream>>>(sums, chunk_off, rp);
    scanC_kernel<<<dim3(SCAN_BLOCKS, 2), SCAN_CHUNK, 0, stream>>>(tmp, chunk_off, rp, cursor);
    colidx_kernel<<<(N_EDGES + 255) / 256, 256, 0, stream>>>(perm, dep, gov, cursor, colf, colr);

    // forward: msg[p] = W_fwd[rel] @ x[gov] + b_fwd, p = perm position
    edge_gemm_p1_kernel<<<dim3(240, N_REL), 256, 0, stream>>>(
        xbf, wt, b_fwd, perm, rel_start, gov, msg, 0);
    reduce_kernel<<<N_NODES, 256, 0, stream>>>(msg, rp, colf, out);
    // reverse: msg[p] = W_rev[rel] @ x[dep] + b_rev (reuses msg buffer)
    edge_gemm_p1_kernel<<<dim3(240, N_REL), 256, 0, stream>>>(
        xbf, wt, b_rev, perm, rel_start, dep, msg, N_REL);
    reduce_kernel<<<N_NODES, 256, 0, stream>>>(msg, rp + (N_NODES + 1), colr, out);
  } else {
    edge_gemm_atomic_kernel<<<dim3(260, 20), 256, 0, stream>>>(
        xbf, wt, b_fwd, b_rev, perm, rel_start, dep, gov, out);
  }
}